// Round 7
// baseline (114.594 us; speedup 1.0000x reference)
//
#include <hip/hip_runtime.h>

// MVB (minimum-variance beamformer), fp32. Round 7: DIAGNOSTIC ROUND.
//
// R5 (1 wave/SIMD) == R6 (2 waves/SIMD, half work/thread) ==> TLP is not the
// limiter, or LB(256,2)'s forced 256-VGPR cap spilled phase B and ate the
// gain. Kernel (~32-36 us by R2-calibrated overhead) hides below the 43-us
// harness ws-poison fill in top-5, so we have zero counter visibility.
// This round: grid x2 -- blocks 512..1023 recompute identically and write to
// d_ws (dead store, no race). The single kernel dispatch (~65-70 us) rises
// above the fills into top-5 WITH its counter row. Also LB(256,1) so the
// allocator is not forced to spill (VGPR_Count column will show the truth).

namespace {

constexpr int kB  = 2;
constexpr int kC  = 128;
constexpr int kNS = 1024;
constexpr int kNZ = 256;
constexpr int kNX = 128;
constexpr int kZX = kNZ * kNX;        // 32768
constexpr int kHalfC = 64;            // channels per half
constexpr int kRows = 4;              // rf rows per half per step (16 KB)
constexpr int kBufF = 2 * kRows * kNS;  // floats per buffer (both halves)
constexpr int kTPB = 256;

// packed upper-triangular index, l <= k, 16x16 -> 136 entries
__device__ __host__ constexpr int tri(int l, int k) {
  return l * 16 - (l * (l - 1)) / 2 + (k - l);
}

typedef __attribute__((address_space(1))) const void gconst_t;
typedef __attribute__((address_space(3))) void ldsv_t;

__device__ __forceinline__ void g2l16(const float* g, float* l) {
  // 16B per lane, LDS dest = wave-uniform base + lane*16
  __builtin_amdgcn_global_load_lds((gconst_t*)g, (ldsv_t*)l, 16, 0, 0);
}

// Stage step q: lower half rows ch = q*4..q*4+3 (waves 0-1), upper half rows
// ch = 64+q*4.. (waves 2-3). Each wave: 8 issues x 1 KB = 8 KB. Async.
__device__ __forceinline__ void stage_step(const float* __restrict__ rfb,
                                           float* tbuf, int q, int wave,
                                           int lane) {
  const int h = wave >> 1;
  const int woff = (wave & 1) * 2048;          // floats within the 16 KB half
  const float* gsrc = rfb + (size_t)(h * kHalfC + q * kRows) * kNS;
  float* ldst = tbuf + h * (kRows * kNS);
#pragma unroll
  for (int i = 0; i < 8; ++i)
    g2l16(gsrc + woff + i * 256 + lane * 4, ldst + woff + i * 256);
}

__device__ __forceinline__ void load_drx4(const float* __restrict__ drxp,
                                          int cbase, float (&d)[kRows]) {
#pragma unroll
  for (int r = 0; r < kRows; ++r)
    d[r] = drxp[(size_t)(cbase + r) * kZX];    // coalesced across lanes
}

template <int PH, bool HEAD>
__device__ __forceinline__ void compute4(
    const float* rows, const float (&drx)[kRows], float kk, float base,
    float (&F)[16], float (&win)[16], float (&head)[16], float& Sall) {
#pragma unroll
  for (int r = 0; r < kRows; ++r) {
    const int t = PH + r;                      // local channel & 15 (static)
    float pos = fmaf(kk, drx[r], base);
    pos = fminf(fmaxf(pos, 0.0f), 1023.0f);
    int i0 = (int)pos;                         // pos >= 0: trunc == floor
    i0 = min(i0, kNS - 2);                     // pos==1023 -> frac==1.0
    float frac = pos - (float)i0;
    const float* p = rows + r * kNS + i0;
    float v0 = p[0];                           // ds_read2_b32 pair
    float v1 = p[1];
    float v = fmaf(frac, v1 - v0, v0);
    Sall += v;
    F[0] = fmaf(v, v, F[0]);
    if constexpr (HEAD) {
#pragma unroll
      for (int d = 1; d <= t; ++d) F[d] = fmaf(v, win[t - d], F[d]);
      head[t] = v;
    } else {
#pragma unroll
      for (int d = 1; d < 16; ++d) F[d] = fmaf(v, win[(t - d) & 15], F[d]);
    }
    win[t] = v;
  }
}

#define STEP(Q, PH, HEADF, CUR, NXT)                                       \
  do {                                                                     \
    if ((Q) + 1 < 16) {                                                    \
      stage_step(rfb, tile[((Q) + 1) & 1], (Q) + 1, wave, lane);           \
      load_drx4(drxp, ((Q) + 1) * kRows, NXT);                             \
    }                                                                      \
    compute4<PH, HEADF>(tile[(Q) & 1] + half * (kRows * kNS), CUR, kk,     \
                        base, F, win, head, Sall);                         \
    __syncthreads();                                                       \
  } while (0)

// ---------------- Fused kernel: split window + combine + solve -------------
__global__ __launch_bounds__(kTPB, 1) void mvb_fused_kernel(
    const float* __restrict__ rf, const float* __restrict__ t0,
    const float* __restrict__ d_tx, const float* __restrict__ d_rx,
    const float* __restrict__ fs_p, const float* __restrict__ c0_p,
    float* __restrict__ out, float* __restrict__ ws) {
  __shared__ float tile[2][kBufF];     // 64 KB double buffer -> 2 blocks/CU

  const int tid = threadIdx.x;
  const int lane = tid & 63;
  const int wave = tid >> 6;
  const int half = tid >> 7;           // 0: ch 0-63, 1: ch 64-127
  const int px = tid & 127;
  const int mirror = blockIdx.x >> 9;  // 0: real, 1: diagnostic duplicate
  const int bid = blockIdx.x & 511;
  const int z = bid & (kNZ - 1);
  const int b = bid >> 8;              // kNZ == 256
  const int pix = (int)((size_t)b * kZX + z * kNX + px);
  float* __restrict__ dst = mirror ? ws : out;  // mirror: dead store to ws

  const float fs = fs_p[0];
  const float c0 = c0_p[0];
  const float kk = fs / c0;
  const float base = fs * (d_tx[pix] / c0 + t0[b]);

  const float* rfb = rf + (size_t)b * kC * kNS;
  const float* drxp =
      d_rx + (size_t)half * kHalfC * kZX + (size_t)z * kNX + px;

  float F[16], win[16], head[16];
  float Sall = 0.0f;
#pragma unroll
  for (int i = 0; i < 16; ++i) F[i] = 0.0f;

  float drxA[kRows], drxB[kRows];

  // ---- phase A: 16 steps of 4 channels per half, double-buffered ----
  stage_step(rfb, tile[0], 0, wave, lane);
  load_drx4(drxp, 0, drxA);
  __syncthreads();

  STEP(0, 0, true, drxA, drxB);
  STEP(1, 4, true, drxB, drxA);
  STEP(2, 8, true, drxA, drxB);
  STEP(3, 12, true, drxB, drxA);
#pragma unroll 1
  for (int g = 1; g < 4; ++g) {
    const int q = g * 4;
    STEP(q + 0, 0, false, drxA, drxB);
    STEP(q + 1, 4, false, drxB, drxA);
    STEP(q + 2, 8, false, drxA, drxB);
    STEP(q + 3, 12, false, drxB, drxA);
  }
  // per half: head[i] = x_{h*64+i}, win[i] = x_{h*64+48+i},
  //           F[d] = sum_{j in half, j-d in half} x_j x_{j-d}

  // ---- exchange: lo exports its 49-float summary via the dead tile ----
  float* xch = tile[0];                // 49*128*4 B = 25 KB < 32 KB
  if (half == 0) {
#pragma unroll
    for (int i = 0; i < 16; ++i) xch[i * 128 + px] = F[i];
#pragma unroll
    for (int i = 0; i < 16; ++i) xch[(16 + i) * 128 + px] = win[i];
#pragma unroll
    for (int i = 0; i < 16; ++i) xch[(32 + i) * 128 + px] = head[i];
    xch[48 * 128 + px] = Sall;
  }
  __syncthreads();
  if (half == 0) return;               // hi waves solve

  float hlo[16];                       // global head = lo's head
  {
    float wlo[16];
#pragma unroll
    for (int i = 0; i < 16; ++i) wlo[i] = xch[(16 + i) * 128 + px];
#pragma unroll
    for (int i = 0; i < 16; ++i) hlo[i] = xch[(32 + i) * 128 + px];
    Sall += xch[48 * 128 + px];
    F[0] += xch[0 * 128 + px];
#pragma unroll
    for (int d = 1; d < 16; ++d) {
      float s = xch[d * 128 + px];     // F_lo[d]
#pragma unroll
      for (int i = 0; i < d; ++i) s = fmaf(head[i], wlo[16 - d + i], s);
      F[d] += s;                       // + cross terms head_hi x win_lo
    }
  }
  // now: hlo = x_{0..15}, win = x_{112..127}, F[d] = full lag sums

  // ---- assemble R (unscaled; packed upper triangle) ----
  float Ru[136];
#pragma unroll
  for (int d = 0; d < 16; ++d) {
    float t0s = 0.0f;                  // tail beyond window of l=0
#pragma unroll
    for (int i = d + 1; i < 16; ++i) t0s = fmaf(win[i - d], win[i], t0s);
    Ru[tri(0, d)] = F[d] - t0s;
#pragma unroll
    for (int l = 1; l < 16 - d; ++l)
      Ru[tri(l, l + d)] = Ru[tri(l - 1, l - 1 + d)] -
                          hlo[l - 1] * hlo[l - 1 + d] +
                          win[l] * win[l + d];
  }

  // diagonal loading: += DL * trace/16
  float tr = 0.0f;
#pragma unroll
  for (int l = 0; l < 16; ++l) tr += Ru[tri(l, l)];
  const float dl = tr * (0.05f / 16.0f);
#pragma unroll
  for (int l = 0; l < 16; ++l) Ru[tri(l, l)] += dl;

  // x (unscaled window sums): X[l] = sum_{j=l}^{l+112} xf[j]
  float X[16];
  {
    float s = Sall;
#pragma unroll
    for (int i = 1; i < 16; ++i) s -= win[i];
    X[0] = s;
#pragma unroll
    for (int l = 1; l < 16; ++l) X[l] = X[l - 1] - hlo[l - 1] + win[l];
  }

  // ---- Cholesky R = L L^T (rsqrt form), L[i][j] at Ru[tri(j,i)] ----
  float inv[16];
#pragma unroll
  for (int j = 0; j < 16; ++j) {
    float d = Ru[tri(j, j)];
#pragma unroll
    for (int p = 0; p < j; ++p) d = fmaf(-Ru[tri(p, j)], Ru[tri(p, j)], d);
    inv[j] = rsqrtf(d);
#pragma unroll
    for (int i = j + 1; i < 16; ++i) {
      float s = Ru[tri(j, i)];
#pragma unroll
      for (int p = 0; p < j; ++p) s = fmaf(-Ru[tri(p, i)], Ru[tri(p, j)], s);
      Ru[tri(j, i)] = s * inv[j];
    }
  }

  // forward solve L y = 1
  float yv[16];
#pragma unroll
  for (int i = 0; i < 16; ++i) {
    float s = 1.0f;
#pragma unroll
    for (int j = 0; j < i; ++j) s = fmaf(-Ru[tri(j, i)], yv[j], s);
    yv[i] = s * inv[i];
  }
  // back solve L^T u = y
  float u[16];
#pragma unroll
  for (int i = 15; i >= 0; --i) {
    float s = yv[i];
#pragma unroll
    for (int j = i + 1; j < 16; ++j) s = fmaf(-Ru[tri(i, j)], u[j], s);
    u[i] = s * inv[i];
  }

  float su = 0.0f, dot = 0.0f;
#pragma unroll
  for (int i = 0; i < 16; ++i) {
    su += u[i];
    dot = fmaf(u[i], X[i], dot);
  }
  // y = dot/(M*su + 1e-10)  (matches reference up to scale algebra)
  dst[pix] = dot / (113.0f * su + 1e-10f);
}

}  // namespace

extern "C" void kernel_launch(void* const* d_in, const int* in_sizes, int n_in,
                              void* d_out, int out_size, void* d_ws,
                              size_t ws_size, hipStream_t stream) {
  const float* rf   = (const float*)d_in[0];
  const float* t0   = (const float*)d_in[1];
  const float* d_tx = (const float*)d_in[2];
  const float* d_rx = (const float*)d_in[3];
  const float* fs   = (const float*)d_in[4];
  // d_in[5] = f0 (unused), d_in[7] = apod (unused by reference)
  const float* c0   = (const float*)d_in[6];
  float* out = (float*)d_out;
  float* ws  = (float*)d_ws;   // mirror-half dead stores (>= 256 KB)

  // grid x2: blocks 512..1023 are diagnostic duplicates writing to ws,
  // lifting the kernel above the 43-us harness fills in rocprof top-5.
  hipLaunchKernelGGL(mvb_fused_kernel, dim3(2 * kB * kNZ), dim3(kTPB), 0,
                     stream, rf, t0, d_tx, d_rx, fs, c0, out, ws);
}

// Round 9
// 100.746 us; speedup vs baseline: 1.1375x; 1.1375x over previous
//
#include <hip/hip_runtime.h>

// MVB (minimum-variance beamformer), fp32. Round 9: exact-count barrier-free.
//
// R8 failed (absmax 7e-2): vmcnt(10) FIFO arithmetic was polluted by the
// outstanding d_tx load, by stage-vs-drx issue reordering inside a step, and
// by a WAR window (DMA overwriting a buffer whose ds_reads could still be in
// flight). R9 makes the counts exact by construction:
//  - all 64 drx preloaded to registers (static indices), then vmcnt(0) once
//    -> the K-loop's vm stream is ONLY staging DMAs (4 per row).
//  - 4 LDS buffers x 1 row (4 KB) per wave, prefetch depth 3:
//    step i: lgkmcnt(0) [WAR guard]; issue row i+3; vmcnt(12) [retires row i
//    exactly]; compute row i. Tail: vmcnt(8/4/0).
//  - 64 steps fully unrolled; no dynamic register indexing anywhere.
// One __syncthreads remains (lo->hi summary exchange).
// Block 256 = 4 waves = 2 pixel-groups x {lo,hi} channel halves; grid 512;
// LDS 64 KB -> 2 blocks/CU -> 2 waves/SIMD.

namespace {

constexpr int kB  = 2;
constexpr int kC  = 128;
constexpr int kNS = 1024;
constexpr int kNZ = 256;
constexpr int kNX = 128;
constexpr int kZX = kNZ * kNX;        // 32768
constexpr int kTPB = 256;

// packed upper-triangular index, l <= k, 16x16 -> 136 entries
__device__ __host__ constexpr int tri(int l, int k) {
  return l * 16 - (l * (l - 1)) / 2 + (k - l);
}

typedef __attribute__((address_space(1))) const void gconst_t;
typedef __attribute__((address_space(3))) void ldsv_t;

__device__ __forceinline__ void g2l16(const float* g, float* l) {
  // 16B per lane, LDS dest = wave-uniform base + lane*16
  __builtin_amdgcn_global_load_lds((gconst_t*)g, (ldsv_t*)l, 16, 0, 0);
}

// Stage one rf row (4 KB) into this wave's private LDS buffer: 4 DMA issues
// of 64 lanes x 16 B. Async (vmcnt).
__device__ __forceinline__ void stage1(const float* __restrict__ g, float* l,
                                       int lane) {
#pragma unroll
  for (int j = 0; j < 4; ++j) g2l16(g + j * 256 + lane * 4, l + j * 256);
}

template <int T, bool HEAD>
__device__ __forceinline__ void compute1(const float* row, float dr, float kk,
                                         float base, float (&F)[16],
                                         float (&win)[16], float (&head)[16],
                                         float& Sall) {
  float pos = fmaf(kk, dr, base);
  pos = fminf(fmaxf(pos, 0.0f), 1023.0f);
  int i0 = (int)pos;                       // pos >= 0: trunc == floor
  i0 = min(i0, kNS - 2);                   // pos==1023 -> frac==1.0
  float frac = pos - (float)i0;
  const float* p = row + i0;
  float v0 = p[0];                         // ds_read2_b32 pair
  float v1 = p[1];
  float v = fmaf(frac, v1 - v0, v0);
  Sall += v;
  F[0] = fmaf(v, v, F[0]);
  if constexpr (HEAD) {
#pragma unroll
    for (int d = 1; d <= T; ++d) F[d] = fmaf(v, win[T - d], F[d]);
    head[T] = v;
  } else {
#pragma unroll
    for (int d = 1; d < 16; ++d) F[d] = fmaf(v, win[(T - d) & 15], F[d]);
  }
  win[T] = v;
}

// One fully-static pipeline step. I, WN literals. vm stream in the loop is
// ONLY stage DMAs (4/row): after issuing row I+3, in-flight rows are
// I..I+3 (16 DMAs); vmcnt(WN=12) retires row I exactly. lgkmcnt(0) ensures
// all prior ds_reads (last reader of the buffer being overwritten: row I-1
// at buffer (I+3)&3) completed before the DMA lands.
#define ST(I, WN, HEADF)                                                   \
  do {                                                                     \
    if ((I) + 3 < 64) {                                                    \
      asm volatile("s_waitcnt lgkmcnt(0)" ::: "memory");                   \
      stage1(rfh + (size_t)((I) + 3) * kNS, ldsw + (((I) + 3) & 3) * 1024, \
             lane);                                                        \
    }                                                                      \
    asm volatile("s_waitcnt vmcnt(" #WN ")" ::: "memory");                 \
    compute1<((I) & 15), (HEADF)>(ldsw + ((I) & 3) * 1024, drx[(I)], kk,   \
                                  base, F, win, head, Sall);               \
  } while (0)

// ---------------- Fused kernel: barrier-free window + solve ----------------
__global__ __launch_bounds__(kTPB, 1) void mvb_fused_kernel(
    const float* __restrict__ rf, const float* __restrict__ t0,
    const float* __restrict__ d_tx, const float* __restrict__ d_rx,
    const float* __restrict__ fs_p, const float* __restrict__ c0_p,
    float* __restrict__ out) {
  __shared__ float lds[4][4096];       // 16 KB private per wave; 64 KB total

  const int tid = threadIdx.x;
  const int lane = tid & 63;
  const int wave = tid >> 6;
  const int half = wave & 1;           // 0: ch 0-63, 1: ch 64-127
  const int grp = wave >> 1;           // pixel group (0: px 0-63, 1: 64-127)
  const int pxr = grp * 64 + lane;     // pixel within the z-row
  const int z = blockIdx.x & (kNZ - 1);
  const int b = blockIdx.x >> 8;       // kNZ == 256
  const int pix = (int)((size_t)b * kZX + z * kNX + pxr);
  float* ldsw = &lds[wave][0];

  const float fs = fs_p[0];
  const float c0 = c0_p[0];
  const float kk = fs / c0;
  const float base = fs * (d_tx[pix] / c0 + t0[b]);

  const float* rfh = rf + (size_t)b * kC * kNS + (size_t)half * 64 * kNS;
  const float* drxp =
      d_rx + (size_t)half * 64 * kZX + (size_t)z * kNX + pxr;

  // ---- preload all 64 per-channel delays into registers (static idx) ----
  float drx[64];
#pragma unroll
  for (int c = 0; c < 64; ++c) drx[c] = drxp[(size_t)c * kZX];

  float F[16], win[16], head[16];
  float Sall = 0.0f;
#pragma unroll
  for (int i = 0; i < 16; ++i) F[i] = 0.0f;

  // Drain drx + d_tx: vm counter is exactly 0 entering the staging loop.
  asm volatile("s_waitcnt vmcnt(0)" ::: "memory");

  // ---- prologue: rows 0..2 in flight (12 DMAs) ----
  stage1(rfh + 0 * kNS, ldsw + 0 * 1024, lane);
  stage1(rfh + 1 * kNS, ldsw + 1 * 1024, lane);
  stage1(rfh + 2 * kNS, ldsw + 2 * 1024, lane);

  // ---- 64 fully-unrolled steps ----
  ST(0, 12, true);  ST(1, 12, true);  ST(2, 12, true);  ST(3, 12, true);
  ST(4, 12, true);  ST(5, 12, true);  ST(6, 12, true);  ST(7, 12, true);
  ST(8, 12, true);  ST(9, 12, true);  ST(10, 12, true); ST(11, 12, true);
  ST(12, 12, true); ST(13, 12, true); ST(14, 12, true); ST(15, 12, true);

  ST(16, 12, false); ST(17, 12, false); ST(18, 12, false); ST(19, 12, false);
  ST(20, 12, false); ST(21, 12, false); ST(22, 12, false); ST(23, 12, false);
  ST(24, 12, false); ST(25, 12, false); ST(26, 12, false); ST(27, 12, false);
  ST(28, 12, false); ST(29, 12, false); ST(30, 12, false); ST(31, 12, false);

  ST(32, 12, false); ST(33, 12, false); ST(34, 12, false); ST(35, 12, false);
  ST(36, 12, false); ST(37, 12, false); ST(38, 12, false); ST(39, 12, false);
  ST(40, 12, false); ST(41, 12, false); ST(42, 12, false); ST(43, 12, false);
  ST(44, 12, false); ST(45, 12, false); ST(46, 12, false); ST(47, 12, false);

  ST(48, 12, false); ST(49, 12, false); ST(50, 12, false); ST(51, 12, false);
  ST(52, 12, false); ST(53, 12, false); ST(54, 12, false); ST(55, 12, false);
  ST(56, 12, false); ST(57, 12, false); ST(58, 12, false); ST(59, 12, false);
  ST(60, 12, false); ST(61, 8, false);  ST(62, 4, false);  ST(63, 0, false);
  // per half: head[i] = x_{h*64+i}, win[i] = x_{h*64+48+i},
  //           F[d] = sum_{j in half, j-d in half} x_j x_{j-d}

  // ---- exchange: lo wave exports summary via its (dead) private region ----
  if (half == 0) {
    float* xo = &lds[wave][0];
#pragma unroll
    for (int i = 0; i < 16; ++i) xo[i * 64 + lane] = F[i];
#pragma unroll
    for (int i = 0; i < 16; ++i) xo[(16 + i) * 64 + lane] = win[i];
#pragma unroll
    for (int i = 0; i < 16; ++i) xo[(32 + i) * 64 + lane] = head[i];
    xo[48 * 64 + lane] = Sall;
  }
  __syncthreads();                     // the ONLY barrier
  if (half == 0) return;               // hi waves solve

  const float* xch = &lds[wave ^ 1][0];  // partner (lo) region
  float hlo[16];                       // global head = lo's head
  {
    float wlo[16];
#pragma unroll
    for (int i = 0; i < 16; ++i) wlo[i] = xch[(16 + i) * 64 + lane];
#pragma unroll
    for (int i = 0; i < 16; ++i) hlo[i] = xch[(32 + i) * 64 + lane];
    Sall += xch[48 * 64 + lane];
    F[0] += xch[0 * 64 + lane];
#pragma unroll
    for (int d = 1; d < 16; ++d) {
      float s = xch[d * 64 + lane];    // F_lo[d]
#pragma unroll
      for (int i = 0; i < d; ++i) s = fmaf(head[i], wlo[16 - d + i], s);
      F[d] += s;                       // + cross terms head_hi x win_lo
    }
  }
  // now: hlo = x_{0..15}, win = x_{112..127}, F[d] = full lag sums

  // ---- assemble R (unscaled; packed upper triangle) ----
  float Ru[136];
#pragma unroll
  for (int d = 0; d < 16; ++d) {
    float t0s = 0.0f;                  // tail beyond window of l=0
#pragma unroll
    for (int i = d + 1; i < 16; ++i) t0s = fmaf(win[i - d], win[i], t0s);
    Ru[tri(0, d)] = F[d] - t0s;
#pragma unroll
    for (int l = 1; l < 16 - d; ++l)
      Ru[tri(l, l + d)] = Ru[tri(l - 1, l - 1 + d)] -
                          hlo[l - 1] * hlo[l - 1 + d] +
                          win[l] * win[l + d];
  }

  // diagonal loading: += DL * trace/16
  float tr = 0.0f;
#pragma unroll
  for (int l = 0; l < 16; ++l) tr += Ru[tri(l, l)];
  const float dl = tr * (0.05f / 16.0f);
#pragma unroll
  for (int l = 0; l < 16; ++l) Ru[tri(l, l)] += dl;

  // x (unscaled window sums): X[l] = sum_{j=l}^{l+112} xf[j]
  float X[16];
  {
    float s = Sall;
#pragma unroll
    for (int i = 1; i < 16; ++i) s -= win[i];
    X[0] = s;
#pragma unroll
    for (int l = 1; l < 16; ++l) X[l] = X[l - 1] - hlo[l - 1] + win[l];
  }

  // ---- Cholesky R = L L^T (rsqrt form), L[i][j] at Ru[tri(j,i)] ----
  float inv[16];
#pragma unroll
  for (int j = 0; j < 16; ++j) {
    float d = Ru[tri(j, j)];
#pragma unroll
    for (int p = 0; p < j; ++p) d = fmaf(-Ru[tri(p, j)], Ru[tri(p, j)], d);
    inv[j] = rsqrtf(d);
#pragma unroll
    for (int i = j + 1; i < 16; ++i) {
      float s = Ru[tri(j, i)];
#pragma unroll
      for (int p = 0; p < j; ++p) s = fmaf(-Ru[tri(p, i)], Ru[tri(p, j)], s);
      Ru[tri(j, i)] = s * inv[j];
    }
  }

  // forward solve L y = 1
  float yv[16];
#pragma unroll
  for (int i = 0; i < 16; ++i) {
    float s = 1.0f;
#pragma unroll
    for (int j = 0; j < i; ++j) s = fmaf(-Ru[tri(j, i)], yv[j], s);
    yv[i] = s * inv[i];
  }
  // back solve L^T u = y
  float u[16];
#pragma unroll
  for (int i = 15; i >= 0; --i) {
    float s = yv[i];
#pragma unroll
    for (int j = i + 1; j < 16; ++j) s = fmaf(-Ru[tri(i, j)], u[j], s);
    u[i] = s * inv[i];
  }

  float su = 0.0f, dot = 0.0f;
#pragma unroll
  for (int i = 0; i < 16; ++i) {
    su += u[i];
    dot = fmaf(u[i], X[i], dot);
  }
  // y = dot/(M*su + 1e-10)  (matches reference up to scale algebra)
  out[pix] = dot / (113.0f * su + 1e-10f);
}

}  // namespace

extern "C" void kernel_launch(void* const* d_in, const int* in_sizes, int n_in,
                              void* d_out, int out_size, void* d_ws,
                              size_t ws_size, hipStream_t stream) {
  const float* rf   = (const float*)d_in[0];
  const float* t0   = (const float*)d_in[1];
  const float* d_tx = (const float*)d_in[2];
  const float* d_rx = (const float*)d_in[3];
  const float* fs   = (const float*)d_in[4];
  // d_in[5] = f0 (unused), d_in[7] = apod (unused by reference)
  const float* c0   = (const float*)d_in[6];
  float* out = (float*)d_out;

  hipLaunchKernelGGL(mvb_fused_kernel, dim3(kB * kNZ), dim3(kTPB), 0, stream,
                     rf, t0, d_tx, d_rx, fs, c0, out);
}

// Round 10
// 94.639 us; speedup vs baseline: 1.2108x; 1.0645x over previous
//
#include <hip/hip_runtime.h>

// MVB (minimum-variance beamformer), fp32. Round 10: LDS-free global gather.
//
// R5/R6/R9 (block-barrier, channel-split, wave-private exact-vmcnt) all land
// at 95-101 us total => the ~24.5 us kernel (measured R7) is bounded by the
// staging+LDS round-trip machinery itself, not barriers or TLP. rf is 1 MB —
// fully L1/L2 resident — so this round gathers DIRECTLY from cache:
//  - 1 thread/pixel, 128 channels, no LDS, no barriers, no DMA.
//  - chunks of 16 channels: 16 coalesced drx loads -> 16 independent 8-B
//    gathers (float2 via memcpy -> global_load_dwordx2, 32 loads in flight;
//    ILP hides L1/L2 latency) -> 16 static-index window-FMA bursts.
//  - chunk size 16 == L_SUB: window indices are compile-time constants.
// Solve phase (R assembly via lag identity + diag load + rsqrt-Cholesky +
// two triangular solves) unchanged from R5 (verified absmax 9.8e-4).

namespace {

constexpr int kB  = 2;
constexpr int kC  = 128;
constexpr int kNS = 1024;
constexpr int kNZ = 256;
constexpr int kNX = 128;
constexpr int kZX = kNZ * kNX;        // 32768
constexpr int kTPB = 256;

// packed upper-triangular index, l <= k, 16x16 -> 136 entries
__device__ __host__ constexpr int tri(int l, int k) {
  return l * 16 - (l * (l - 1)) / 2 + (k - l);
}

template <bool HEAD>
__device__ __forceinline__ void chunk16(
    const float* __restrict__ rfq,       // rfb + q*16*kNS
    const float* __restrict__ drxp, int cbase, float kk, float base,
    float (&F)[16], float (&win)[16], float (&head)[16], float& Sall) {
  // 16 coalesced per-channel delays (independent, deep in flight)
  float dr[16];
#pragma unroll
  for (int r = 0; r < 16; ++r) dr[r] = drxp[(size_t)(cbase + r) * kZX];

  // 16 independent 8-byte gathers from the L1/L2-resident rf rows
  float2 vv[16];
  float fr[16];
#pragma unroll
  for (int r = 0; r < 16; ++r) {
    float pos = fmaf(kk, dr[r], base);
    pos = fminf(fmaxf(pos, 0.0f), 1023.0f);
    int i0 = (int)pos;                   // pos >= 0: trunc == floor
    i0 = min(i0, kNS - 2);               // pos==1023 -> frac==1.0
    fr[r] = pos - (float)i0;
    __builtin_memcpy(&vv[r], rfq + r * kNS + i0, 8);   // v0,v1 adjacent
  }

  // window-FMA bursts; chunk aligns with L_SUB so indices are static
#pragma unroll
  for (int r = 0; r < 16; ++r) {
    float v = fmaf(fr[r], vv[r].y - vv[r].x, vv[r].x);
    Sall += v;
    F[0] = fmaf(v, v, F[0]);
    if constexpr (HEAD) {
#pragma unroll
      for (int d = 1; d <= r; ++d) F[d] = fmaf(v, win[r - d], F[d]);
      head[r] = v;
    } else {
#pragma unroll
      for (int d = 1; d < 16; ++d) F[d] = fmaf(v, win[(r - d) & 15], F[d]);
    }
    win[r] = v;
  }
}

// ---------------- Fused kernel: gather + window + solve, no LDS ------------
__global__ __launch_bounds__(kTPB, 1) void mvb_kernel(
    const float* __restrict__ rf, const float* __restrict__ t0,
    const float* __restrict__ d_tx, const float* __restrict__ d_rx,
    const float* __restrict__ fs_p, const float* __restrict__ c0_p,
    float* __restrict__ out) {
  const int tid = threadIdx.x;
  const int b = blockIdx.x >> 7;         // 256 blocks: b in {0,1}
  const int z = ((blockIdx.x & 127) << 1) + (tid >> 7);
  const int x = tid & 127;
  const int pix = (int)((size_t)b * kZX + z * kNX + x);

  const float fs = fs_p[0];
  const float c0 = c0_p[0];
  const float kk = fs / c0;
  const float base = fs * (d_tx[pix] / c0 + t0[b]);

  const float* rfb = rf + (size_t)b * kC * kNS;
  const float* drxp = d_rx + (size_t)z * kNX + x;   // + c*kZX per channel

  float F[16], win[16], head[16];
  float Sall = 0.0f;
#pragma unroll
  for (int i = 0; i < 16; ++i) F[i] = 0.0f;

  // ---- phase A: 8 chunks of 16 channels ----
  chunk16<true>(rfb, drxp, 0, kk, base, F, win, head, Sall);
#pragma unroll 1
  for (int q = 1; q < 8; ++q)
    chunk16<false>(rfb + (size_t)q * 16 * kNS, drxp, q * 16, kk, base, F, win,
                   head, Sall);
  // now: head[i] = xf[i], win[i] = xf[112+i], F[d] = sum_j xf[j]*xf[j-d]

  // ---- assemble R (unscaled; packed upper triangle) ----
  float Ru[136];
#pragma unroll
  for (int d = 0; d < 16; ++d) {
    float t0s = 0.0f;                    // tail beyond window of l=0
#pragma unroll
    for (int i = d + 1; i < 16; ++i) t0s = fmaf(win[i - d], win[i], t0s);
    Ru[tri(0, d)] = F[d] - t0s;
#pragma unroll
    for (int l = 1; l < 16 - d; ++l)
      Ru[tri(l, l + d)] = Ru[tri(l - 1, l - 1 + d)] -
                          head[l - 1] * head[l - 1 + d] +
                          win[l] * win[l + d];
  }

  // diagonal loading: += DL * trace/16
  float tr = 0.0f;
#pragma unroll
  for (int l = 0; l < 16; ++l) tr += Ru[tri(l, l)];
  const float dl = tr * (0.05f / 16.0f);
#pragma unroll
  for (int l = 0; l < 16; ++l) Ru[tri(l, l)] += dl;

  // x (unscaled window sums): X[l] = sum_{j=l}^{l+112} xf[j]
  float X[16];
  {
    float s = Sall;
#pragma unroll
    for (int i = 1; i < 16; ++i) s -= win[i];
    X[0] = s;
#pragma unroll
    for (int l = 1; l < 16; ++l) X[l] = X[l - 1] - head[l - 1] + win[l];
  }

  // ---- Cholesky R = L L^T (rsqrt form), L[i][j] at Ru[tri(j,i)] ----
  float inv[16];
#pragma unroll
  for (int j = 0; j < 16; ++j) {
    float d = Ru[tri(j, j)];
#pragma unroll
    for (int p = 0; p < j; ++p) d = fmaf(-Ru[tri(p, j)], Ru[tri(p, j)], d);
    inv[j] = rsqrtf(d);
#pragma unroll
    for (int i = j + 1; i < 16; ++i) {
      float s = Ru[tri(j, i)];
#pragma unroll
      for (int p = 0; p < j; ++p) s = fmaf(-Ru[tri(p, i)], Ru[tri(p, j)], s);
      Ru[tri(j, i)] = s * inv[j];
    }
  }

  // forward solve L y = 1
  float yv[16];
#pragma unroll
  for (int i = 0; i < 16; ++i) {
    float s = 1.0f;
#pragma unroll
    for (int j = 0; j < i; ++j) s = fmaf(-Ru[tri(j, i)], yv[j], s);
    yv[i] = s * inv[i];
  }
  // back solve L^T u = y
  float u[16];
#pragma unroll
  for (int i = 15; i >= 0; --i) {
    float s = yv[i];
#pragma unroll
    for (int j = i + 1; j < 16; ++j) s = fmaf(-Ru[tri(i, j)], u[j], s);
    u[i] = s * inv[i];
  }

  float su = 0.0f, dot = 0.0f;
#pragma unroll
  for (int i = 0; i < 16; ++i) {
    su += u[i];
    dot = fmaf(u[i], X[i], dot);
  }
  // y = dot/(M*su + 1e-10)  (matches reference up to scale algebra)
  out[pix] = dot / (113.0f * su + 1e-10f);
}

}  // namespace

extern "C" void kernel_launch(void* const* d_in, const int* in_sizes, int n_in,
                              void* d_out, int out_size, void* d_ws,
                              size_t ws_size, hipStream_t stream) {
  const float* rf   = (const float*)d_in[0];
  const float* t0   = (const float*)d_in[1];
  const float* d_tx = (const float*)d_in[2];
  const float* d_rx = (const float*)d_in[3];
  const float* fs   = (const float*)d_in[4];
  // d_in[5] = f0 (unused), d_in[7] = apod (unused by reference)
  const float* c0   = (const float*)d_in[6];
  float* out = (float*)d_out;

  hipLaunchKernelGGL(mvb_kernel, dim3(kB * kNZ / 2), dim3(kTPB), 0, stream,
                     rf, t0, d_tx, d_rx, fs, c0, out);
}